// Round 3
// baseline (509.566 us; speedup 1.0000x reference)
//
#include <hip/hip_runtime.h>

#define BB 4
#define CC 96
#define LL 32
#define HH 56
#define WW 56
#define HW (HH * WW)
#define KD 16
#define TW 28   // output tile for register-blocked conv (2 tiles of 28 = 56)

// ---------------------------------------------------------------------------
// Pass 1: fused causal conv along W then H, per (b,c,l) 56x56 slice.
// grid.x = B*C*L/4, 256 threads; each 64-lane wave owns one slice.
// Register discipline: xr[56] + acc[28] live (≈95 VGPR) — no scratch spill.
// ---------------------------------------------------------------------------
__global__ __launch_bounds__(256, 3) void conv_wh(const float* __restrict__ x,
                                                  const float* __restrict__ wconv,
                                                  const float* __restrict__ hconv,
                                                  float* __restrict__ out) {
    __shared__ float sl[4][HH][WW + 1];   // +1 pad: odd stride -> conflict-free
    __shared__ float wk[WW];
    __shared__ float hk[HH];

    const int tid  = threadIdx.x;
    const int wv   = tid >> 6;
    const int lane = tid & 63;
    const int slice0 = blockIdx.x * 4;                 // 4 slices, same (b,c)
    const int c      = (slice0 / LL) % CC;

    if (tid < WW)                      wk[tid]      = wconv[c * WW + tid];
    else if (tid >= 64 && tid < 64+HH) hk[tid - 64] = hconv[c * HH + (tid - 64)];

    // cooperative coalesced load: each wave loads its slice (3136 = 49*64)
    const size_t base = (size_t)(slice0 + wv) * HW;
    #pragma unroll
    for (int i = 0; i < HW / 64; ++i) {
        int m = i * 64 + lane;
        sl[wv][m / WW][m % WW] = x[base + m];
    }
    __syncthreads();

    // ---- W pass: lane = row h ----
    if (lane < HH) {
        float xr[WW];
        #pragma unroll
        for (int j = 0; j < WW; ++j) xr[j] = sl[wv][lane][j];

        #pragma unroll
        for (int t = 0; t < 2; ++t) {
            const int w0 = t * TW;
            float acc[TW];
            #pragma unroll
            for (int i = 0; i < TW; ++i) acc[i] = 0.f;
            #pragma unroll
            for (int d = 0; d < 2 * TW; ++d) {        // only d < w0+TW contribute
                if (d < w0 + TW) {
                    const float kd = wk[d];           // 1 LDS broadcast per ≤28 FMAs
                    #pragma unroll
                    for (int i = 0; i < TW; ++i)
                        if (w0 + i >= d)
                            acc[i] = fmaf(kd, xr[w0 + i - d], acc[i]);
                }
            }
            #pragma unroll
            for (int i = 0; i < TW; ++i) sl[wv][lane][w0 + i] = acc[i];  // xr is a copy
        }
    }
    __syncthreads();

    // ---- H pass: lane = column w ----
    if (lane < WW) {
        float xr[HH];
        #pragma unroll
        for (int h = 0; h < HH; ++h) xr[h] = sl[wv][h][lane];

        #pragma unroll
        for (int t = 0; t < 2; ++t) {
            const int h0 = t * TW;
            float acc[TW];
            #pragma unroll
            for (int i = 0; i < TW; ++i) acc[i] = 0.f;
            #pragma unroll
            for (int d = 0; d < 2 * TW; ++d) {
                if (d < h0 + TW) {
                    const float kd = hk[d];
                    #pragma unroll
                    for (int i = 0; i < TW; ++i)
                        if (h0 + i >= d)
                            acc[i] = fmaf(kd, xr[h0 + i - d], acc[i]);
                }
            }
            #pragma unroll
            for (int i = 0; i < TW; ++i)
                out[base + (size_t)(h0 + i) * WW + lane] = acc[i];
        }
    }
}

// ---------------------------------------------------------------------------
// Pass 2: causal conv along L, in-place on out. One thread per (b,c,h,w)
// column; reads all 32 before writing -> in-place is race-free.
// ---------------------------------------------------------------------------
__global__ __launch_bounds__(256, 4) void conv_l(float* __restrict__ y,
                                                 const float* __restrict__ k0,
                                                 const float* __restrict__ k1,
                                                 const float* __restrict__ decay) {
    __shared__ float kl[LL];
    __shared__ float s_norm;

    const int tid = threadIdx.x;
    const int bc  = blockIdx.y;             // b*C + c
    const int c   = bc % CC;

    if (tid < LL) {
        float v;
        const float dec = decay[c];
        if (tid < KD) {
            v = k0[c * KD + tid] * dec;     // kernel0 * decay^1
        } else {
            // linear interp (scale=2, align_corners=False) of kernel1, first 16
            const int   i    = tid - KD;
            const float src  = fmaxf((i + 0.5f) * 0.5f - 0.5f, 0.f);
            const int   lo   = (int)floorf(src);
            const float frac = src - (float)lo;
            const int   hi   = min(lo + 1, KD - 1);
            v = k1[c * KD + lo] * (1.f - frac) + k1[c * KD + hi] * frac;
        }
        kl[tid] = v;
    }
    __syncthreads();
    if (tid == 0) {
        float s = 0.f;
        for (int i = 0; i < LL; ++i) s += kl[i] * kl[i];
        s_norm = sqrtf(s);
    }
    __syncthreads();

    const float inv = 1.0f / s_norm;
    float kr[LL];
    #pragma unroll
    for (int i = 0; i < LL; ++i) kr[i] = kl[i] * inv;

    const int pos = blockIdx.x * 256 + tid;
    if (pos >= HW) return;

    float* col = y + (size_t)bc * LL * HW + pos;
    float xin[LL];
    #pragma unroll
    for (int l = 0; l < LL; ++l) xin[l] = col[(size_t)l * HW];

    // in-place causal conv, descending l: xin[j<l] still original when used
    #pragma unroll
    for (int l = LL - 1; l >= 0; --l) {
        float t = 0.f;
        #pragma unroll
        for (int j = 0; j <= l; ++j)
            t = fmaf(kr[l - j], xin[j], t);
        xin[l] = t;
    }
    #pragma unroll
    for (int l = 0; l < LL; ++l) col[(size_t)l * HW] = xin[l];
}

// ---------------------------------------------------------------------------
extern "C" void kernel_launch(void* const* d_in, const int* in_sizes, int n_in,
                              void* d_out, int out_size, void* d_ws, size_t ws_size,
                              hipStream_t stream) {
    const float* x     = (const float*)d_in[0];
    const float* wconv = (const float*)d_in[1];
    const float* hconv = (const float*)d_in[2];
    const float* k0    = (const float*)d_in[3];
    const float* k1    = (const float*)d_in[4];
    const float* dec   = (const float*)d_in[5];
    float*       out   = (float*)d_out;

    conv_wh<<<dim3(BB * CC * LL / 4), 256, 0, stream>>>(x, wconv, hconv, out);
    conv_l<<<dim3((HW + 255) / 256, BB * CC), 256, 0, stream>>>(out, k0, k1, dec);
}

// Round 4
// 342.190 us; speedup vs baseline: 1.4891x; 1.4891x over previous
//
#include <hip/hip_runtime.h>

#define BB 4
#define CC 96
#define LL 32
#define HH 56
#define WW 56
#define HW (HH * WW)
#define KD 16
#define CH 14   // chunk/tile size: live set = acc[14]+xch[14] -> never spills

// ---------------------------------------------------------------------------
// Pass 1: fused causal conv along W then H, per (b,c,l) 56x56 slice.
// 4 waves/block, each wave owns one slice (4 consecutive l, same (b,c)).
// Tiled in-place triangular conv: output tiles DESCENDING so tile t only
// overwrites input chunk t (needed only by itself). Taps via uniform global
// reads -> s_load -> SGPR operand of v_fma (no LDS traffic for taps).
// ---------------------------------------------------------------------------
__global__ __launch_bounds__(256, 3) void conv_wh(const float* __restrict__ x,
                                                  const float* __restrict__ wconv,
                                                  const float* __restrict__ hconv,
                                                  float* __restrict__ out) {
    __shared__ float sl[4][HH][WW + 1];   // +1 pad: odd stride -> conflict-free

    const int tid  = threadIdx.x;
    const int wv   = tid >> 6;
    const int lane = tid & 63;
    const int slice0 = blockIdx.x * 4;
    const int c      = (slice0 / LL) % CC;
    const float* __restrict__ kw = wconv + c * WW;   // uniform -> scalar loads
    const float* __restrict__ kh = hconv + c * HH;

    // cooperative coalesced load: each wave loads its slice (3136 = 49*64)
    const size_t base = (size_t)(slice0 + wv) * HW;
    #pragma unroll
    for (int i = 0; i < HW / 64; ++i) {
        int m = i * 64 + lane;
        sl[wv][m / WW][m % WW] = x[base + m];
    }
    __syncthreads();

    // ---- W pass: lane = row h; in-place on the row, tiles descending ----
    if (lane < HH) {
        float* row = &sl[wv][lane][0];
        #pragma unroll
        for (int t = 3; t >= 0; --t) {
            const int w0 = t * CH;
            float acc[CH];
            #pragma unroll
            for (int i = 0; i < CH; ++i) acc[i] = 0.f;
            // off-diagonal input chunks u < t (full 27-diagonal band)
            #pragma unroll
            for (int u = 0; u < t; ++u) {
                const int u0 = u * CH;
                float xch[CH];
                #pragma unroll
                for (int j = 0; j < CH; ++j) xch[j] = row[u0 + j];
                #pragma unroll
                for (int dd = 0; dd < 2 * CH - 1; ++dd) {
                    const float kd = kw[w0 - u0 - (CH - 1) + dd];
                    const int delta = dd - (CH - 1);
                    #pragma unroll
                    for (int j = 0; j < CH; ++j) {
                        const int i = j + delta;
                        if (i >= 0 && i < CH)
                            acc[i] = fmaf(kd, xch[j], acc[i]);
                    }
                }
            }
            // diagonal chunk (u == t): triangular
            {
                float xch[CH];
                #pragma unroll
                for (int j = 0; j < CH; ++j) xch[j] = row[w0 + j];
                #pragma unroll
                for (int dd = 0; dd < CH; ++dd) {
                    const float kd = kw[dd];
                    #pragma unroll
                    for (int j = 0; j < CH - dd; ++j)
                        acc[j + dd] = fmaf(kd, xch[j], acc[j + dd]);
                }
            }
            #pragma unroll
            for (int i = 0; i < CH; ++i) row[w0 + i] = acc[i];
        }
    }
    __syncthreads();

    // ---- H pass: lane = column w; reads columns, writes global ----
    if (lane < WW) {
        #pragma unroll
        for (int t = 3; t >= 0; --t) {
            const int h0 = t * CH;
            float acc[CH];
            #pragma unroll
            for (int i = 0; i < CH; ++i) acc[i] = 0.f;
            #pragma unroll
            for (int u = 0; u < t; ++u) {
                const int u0 = u * CH;
                float xch[CH];
                #pragma unroll
                for (int j = 0; j < CH; ++j) xch[j] = sl[wv][u0 + j][lane];
                #pragma unroll
                for (int dd = 0; dd < 2 * CH - 1; ++dd) {
                    const float kd = kh[h0 - u0 - (CH - 1) + dd];
                    const int delta = dd - (CH - 1);
                    #pragma unroll
                    for (int j = 0; j < CH; ++j) {
                        const int i = j + delta;
                        if (i >= 0 && i < CH)
                            acc[i] = fmaf(kd, xch[j], acc[i]);
                    }
                }
            }
            {
                float xch[CH];
                #pragma unroll
                for (int j = 0; j < CH; ++j) xch[j] = sl[wv][h0 + j][lane];
                #pragma unroll
                for (int dd = 0; dd < CH; ++dd) {
                    const float kd = kh[dd];
                    #pragma unroll
                    for (int j = 0; j < CH - dd; ++j)
                        acc[j + dd] = fmaf(kd, xch[j], acc[j + dd]);
                }
            }
            #pragma unroll
            for (int i = 0; i < CH; ++i)
                out[base + (size_t)(h0 + i) * WW + lane] = acc[i];
        }
    }
}

// ---------------------------------------------------------------------------
// Pass 2: causal conv along L, in-place on out. One thread per (b,c,h,w)
// column; reads all 32 before writing -> in-place is race-free.
// ---------------------------------------------------------------------------
__global__ __launch_bounds__(256, 2) void conv_l(float* __restrict__ y,
                                                 const float* __restrict__ k0,
                                                 const float* __restrict__ k1,
                                                 const float* __restrict__ decay) {
    __shared__ float kl[LL];
    __shared__ float s_norm;

    const int tid = threadIdx.x;
    const int bc  = blockIdx.y;             // b*C + c
    const int c   = bc % CC;

    if (tid < LL) {
        float v;
        const float dec = decay[c];
        if (tid < KD) {
            v = k0[c * KD + tid] * dec;     // kernel0 * decay^1
        } else {
            // linear interp (scale=2, align_corners=False) of kernel1, first 16
            const int   i    = tid - KD;
            const float src  = fmaxf((i + 0.5f) * 0.5f - 0.5f, 0.f);
            const int   lo   = (int)floorf(src);
            const float frac = src - (float)lo;
            const int   hi   = min(lo + 1, KD - 1);
            v = k1[c * KD + lo] * (1.f - frac) + k1[c * KD + hi] * frac;
        }
        kl[tid] = v;
    }
    __syncthreads();
    if (tid == 0) {
        float s = 0.f;
        for (int i = 0; i < LL; ++i) s += kl[i] * kl[i];
        s_norm = sqrtf(s);
    }
    __syncthreads();

    const float inv = 1.0f / s_norm;
    float kr[LL];
    #pragma unroll
    for (int i = 0; i < LL; ++i) kr[i] = kl[i] * inv;

    const int pos = blockIdx.x * 256 + tid;
    if (pos >= HW) return;

    float* col = y + (size_t)bc * LL * HW + pos;
    float xin[LL];
    #pragma unroll
    for (int l = 0; l < LL; ++l) xin[l] = col[(size_t)l * HW];

    // in-place causal conv, descending l: xin[j<l] still original when used
    #pragma unroll
    for (int l = LL - 1; l >= 0; --l) {
        float t = 0.f;
        #pragma unroll
        for (int j = 0; j <= l; ++j)
            t = fmaf(kr[l - j], xin[j], t);
        xin[l] = t;
    }
    #pragma unroll
    for (int l = 0; l < LL; ++l) col[(size_t)l * HW] = xin[l];
}

// ---------------------------------------------------------------------------
extern "C" void kernel_launch(void* const* d_in, const int* in_sizes, int n_in,
                              void* d_out, int out_size, void* d_ws, size_t ws_size,
                              hipStream_t stream) {
    const float* x     = (const float*)d_in[0];
    const float* wconv = (const float*)d_in[1];
    const float* hconv = (const float*)d_in[2];
    const float* k0    = (const float*)d_in[3];
    const float* k1    = (const float*)d_in[4];
    const float* dec   = (const float*)d_in[5];
    float*       out   = (float*)d_out;

    conv_wh<<<dim3(BB * CC * LL / 4), 256, 0, stream>>>(x, wconv, hconv, out);
    conv_l<<<dim3((HW + 255) / 256, BB * CC), 256, 0, stream>>>(out, k0, k1, dec);
}